// Round 1
// baseline (3526.498 us; speedup 1.0000x reference)
//
#include <hip/hip_runtime.h>
#include <math.h>

#define EDGES_F 128
#define MULC 64
#define HID_C 128

// ---- host-side constant: SILU_C exactly as the reference computes it ----
static float compute_inv_silu_c() {
    double sum = 0.0, prev = 0.0;
    const double dz = 24.0 / 100000.0;
    for (int i = 0; i <= 100000; ++i) {
        double z = -12.0 + dz * (double)i;
        double pdf = exp(-0.5 * z * z) * 0.3989422804014327;  // 1/sqrt(2pi)
        double s = z / (1.0 + exp(-z));
        double f = s * s * pdf;
        if (i) sum += 0.5 * (prev + f) * dz;
        prev = f;
    }
    return (float)(1.0 / sqrt(sum));
}
static const float INV_SILU_C = compute_inv_silu_c();

// ---- device helpers ----
__device__ __forceinline__ unsigned int packbf(float a, float b) {
    union { float f; unsigned int u; } ca, cb;
    ca.f = a; cb.f = b;
    unsigned int ua = ca.u + (0x7fffu + ((ca.u >> 16) & 1u));
    unsigned int ub = cb.u + (0x7fffu + ((cb.u >> 16) & 1u));
    return (ua >> 16) | (ub & 0xffff0000u);
}
__device__ __forceinline__ float bflo(unsigned int u) { return __uint_as_float(u << 16); }
__device__ __forceinline__ float bfhi(unsigned int u) { return __uint_as_float(u & 0xffff0000u); }
__device__ __forceinline__ float nsilu(float v, float inv_c) {
    return v / (1.0f + __expf(-v)) * inv_c;
}

// =====================================================================
// Kernel 1: per-edge w = (x*m) @ W_env/sqrt(128); scatter ws, wv, m into
// node accumulators with f32 atomics.
// =====================================================================
__global__ __launch_bounds__(1024) void k_scatter(
    const float* __restrict__ vectors, const float* __restrict__ x,
    const float* __restrict__ m, const float* __restrict__ W_env,
    const int* __restrict__ senders,
    float* __restrict__ node_cnt, float* __restrict__ node_s,
    float* __restrict__ node_v, int E)
{
    __shared__ float sW[128 * 128];
    for (int t = threadIdx.x; t < 128 * 128; t += 1024)
        sW[t] = W_env[t] * 0.08838834764831845f;  // fold 1/sqrt(128)
    __syncthreads();

    const int lane = threadIdx.x & 63;
    const int gw   = (int)((blockIdx.x * 1024u + threadIdx.x) >> 6);
    const int nw   = (int)((gridDim.x * 1024u) >> 6);

    for (int e = gw; e < E; e += nw) {
        const float mv = m[e];
        const float x0 = x[(size_t)e * 128 + lane] * mv;
        const float x1 = x[(size_t)e * 128 + 64 + lane] * mv;

        float acc0 = 0.f, acc1 = 0.f;  // w0[lane], w1[lane]
        #pragma unroll 8
        for (int q = 0; q < 64; ++q) {
            const float xa = __shfl(x0, q);   // xm[q]
            const float xb = __shfl(x1, q);   // xm[64+q]
            acc0 += xa * sW[q * 128 + lane]        + xb * sW[(64 + q) * 128 + lane];
            acc1 += xa * sW[q * 128 + 64 + lane]   + xb * sW[(64 + q) * 128 + 64 + lane];
        }

        const float vx = vectors[(size_t)e * 3 + 0];
        const float vy = vectors[(size_t)e * 3 + 1];
        const float vz = vectors[(size_t)e * 3 + 2];
        const float rn = 1.7320508075688772f / sqrtf(vx * vx + vy * vy + vz * vz);

        const int sn = senders[e];
        const float wsv = acc0 * mv;
        const float c1  = acc1 * mv;
        atomicAdd(&node_s[(size_t)sn * 64 + lane], wsv);
        float* nv = &node_v[((size_t)sn * 64 + lane) * 3];
        atomicAdd(nv + 0, c1 * vx * rn);
        atomicAdd(nv + 1, c1 * vy * rn);
        atomicAdd(nv + 2, c1 * vz * rn);
        if (lane == 0) atomicAdd(&node_cnt[sn], mv);
    }
}

// =====================================================================
// Kernel 2: gather node sums; compute s_a/s_b/v_a/v_b; fused MLP
// (W1,W2,W3 bf16 in LDS) and V_out (W_out bf16 in LDS).
// =====================================================================
__global__ __launch_bounds__(1024) void k_fused(
    const float* __restrict__ x, const float* __restrict__ V,
    const float* __restrict__ u, const float* __restrict__ m,
    const float* __restrict__ W1, const float* __restrict__ W2,
    const float* __restrict__ W3, const float* __restrict__ Wout,
    const int* __restrict__ senders,
    const float* __restrict__ node_cnt, const float* __restrict__ node_s,
    const float* __restrict__ node_v,
    float* __restrict__ out_x, float* __restrict__ out_v,
    float inv_c, int E)
{
    // packed bf16 weight pairs (columns 2p,2p+1), scales folded in
    __shared__ unsigned int w1p[256 * 64];  // 64 KB
    __shared__ unsigned int w2p[128 * 64];  // 32 KB
    __shared__ unsigned int w3p[128 * 64];  // 32 KB
    __shared__ unsigned int wop[64 * 64];   // 16 KB  (u-pairs x o)

    for (int t = threadIdx.x; t < 256 * 64; t += 1024) {
        int i = t >> 6, p = t & 63;
        w1p[t] = packbf(W1[i * 128 + 2 * p] * 0.0625f, W1[i * 128 + 2 * p + 1] * 0.0625f);
    }
    for (int t = threadIdx.x; t < 128 * 64; t += 1024) {
        int i = t >> 6, p = t & 63;
        w2p[t] = packbf(W2[i * 128 + 2 * p] * 0.08838834764831845f,
                        W2[i * 128 + 2 * p + 1] * 0.08838834764831845f);
        w3p[t] = packbf(W3[i * 128 + 2 * p] * 0.08838834764831845f,
                        W3[i * 128 + 2 * p + 1] * 0.08838834764831845f);
    }
    for (int t = threadIdx.x; t < 64 * 64; t += 1024) {
        int q = t >> 6, o = t & 63;  // u-pair q -> u=2q,2q+1
        wop[t] = packbf(Wout[(2 * q) * 64 + o] * 0.08838834764831845f,
                        Wout[(2 * q + 1) * 64 + o] * 0.08838834764831845f);
    }
    __syncthreads();

    const int lane = threadIdx.x & 63;
    const int gw   = (int)((blockIdx.x * 1024u + threadIdx.x) >> 6);
    const int nw   = (int)((gridDim.x * 1024u) >> 6);

    for (int e = gw; e < E; e += nw) {
        const int sn = senders[e];
        const float rden = 1.0f / (node_cnt[sn] + 1e-5f);
        const float wYs = node_s[(size_t)sn * 64 + lane] * rden;
        const float* nv = &node_v[((size_t)sn * 64 + lane) * 3];
        const float wv0 = nv[0] * rden, wv1 = nv[1] * rden, wv2 = nv[2] * rden;

        const float Vs  = V[(size_t)e * 256 + lane];
        const float* vvp = &V[(size_t)e * 256 + 64 + lane * 3];
        const float Vv0 = vvp[0], Vv1 = vvp[1], Vv2 = vvp[2];

        const float s_a = wYs * Vs;
        const float s_b = (wv0 * Vv0 + wv1 * Vv1 + wv2 * Vv2) * 0.57735026918962576f;
        const float va0 = wYs * Vv0, va1 = wYs * Vv1, va2 = wYs * Vv2;
        const float vb0 = wv0 * Vs,  vb1 = wv1 * Vs,  vb2 = wv2 * Vs;

        const float mv  = m[e];
        const float xc0 = x[(size_t)e * 128 + lane] * mv;        // xcat[0..63]
        const float xc1 = x[(size_t)e * 128 + 64 + lane] * mv;   // xcat[64..127]
        // xcat[128..191] = s_a, xcat[192..255] = s_b

        // ---- stage 1: h = nsilu(xcat @ W1 / 16); lane owns j=2l,2l+1 ----
        float h0 = 0.f, h1 = 0.f;
        auto gemv_seg = [&](float reg, int base) {
            #pragma unroll 8
            for (int q = 0; q < 64; ++q) {
                const float xi = __shfl(reg, q);
                const unsigned int w = w1p[(base + q) * 64 + lane];
                h0 += xi * bflo(w);
                h1 += xi * bfhi(w);
            }
        };
        gemv_seg(xc0, 0);
        gemv_seg(xc1, 64);
        gemv_seg(s_a, 128);
        gemv_seg(s_b, 192);
        h0 = nsilu(h0, inv_c);
        h1 = nsilu(h1, inv_c);

        // ---- stage 2 ----
        float g0 = 0.f, g1 = 0.f;
        #pragma unroll 8
        for (int q = 0; q < 64; ++q) {
            const float a = __shfl(h0, q);   // i = 2q
            const float b = __shfl(h1, q);   // i = 2q+1
            const unsigned int wa = w2p[(2 * q) * 64 + lane];
            const unsigned int wb = w2p[(2 * q + 1) * 64 + lane];
            g0 += a * bflo(wa) + b * bflo(wb);
            g1 += a * bfhi(wa) + b * bfhi(wb);
        }
        g0 = nsilu(g0, inv_c);
        g1 = nsilu(g1, inv_c);

        // ---- stage 3 (no activation) ----
        float f0 = 0.f, f1 = 0.f;
        #pragma unroll 8
        for (int q = 0; q < 64; ++q) {
            const float a = __shfl(g0, q);
            const float b = __shfl(g1, q);
            const unsigned int wa = w3p[(2 * q) * 64 + lane];
            const unsigned int wb = w3p[(2 * q + 1) * 64 + lane];
            f0 += a * bflo(wa) + b * bflo(wb);
            f1 += a * bfhi(wa) + b * bfhi(wb);
        }
        const float ue = u[e];
        out_x[(size_t)e * 128 + 2 * lane]     = ue * f0;
        out_x[(size_t)e * 128 + 2 * lane + 1] = ue * f1;

        // ---- V_out: lane owns o=lane, k=0..2 ----
        float o0 = 0.f, o1 = 0.f, o2 = 0.f;
        #pragma unroll 8
        for (int q = 0; q < 32; ++q) {  // u = 2q, 2q+1 (v_a half)
            const float a0 = __shfl(va0, 2 * q),     a1 = __shfl(va1, 2 * q),     a2 = __shfl(va2, 2 * q);
            const float b0 = __shfl(va0, 2 * q + 1), b1 = __shfl(va1, 2 * q + 1), b2 = __shfl(va2, 2 * q + 1);
            const unsigned int w = wop[q * 64 + lane];
            const float wl = bflo(w), wh = bfhi(w);
            o0 += a0 * wl + b0 * wh;
            o1 += a1 * wl + b1 * wh;
            o2 += a2 * wl + b2 * wh;
        }
        #pragma unroll 8
        for (int q = 0; q < 32; ++q) {  // u = 64+2q, 64+2q+1 (v_b half)
            const float a0 = __shfl(vb0, 2 * q),     a1 = __shfl(vb1, 2 * q),     a2 = __shfl(vb2, 2 * q);
            const float b0 = __shfl(vb0, 2 * q + 1), b1 = __shfl(vb1, 2 * q + 1), b2 = __shfl(vb2, 2 * q + 1);
            const unsigned int w = wop[(32 + q) * 64 + lane];
            const float wl = bflo(w), wh = bfhi(w);
            o0 += a0 * wl + b0 * wh;
            o1 += a1 * wl + b1 * wh;
            o2 += a2 * wl + b2 * wh;
        }
        float* ov = &out_v[(size_t)e * 192 + lane * 3];
        ov[0] = o0; ov[1] = o1; ov[2] = o2;
    }
}

// =====================================================================
extern "C" void kernel_launch(void* const* d_in, const int* in_sizes, int n_in,
                              void* d_out, int out_size, void* d_ws, size_t ws_size,
                              hipStream_t stream) {
    const float* vectors = (const float*)d_in[0];
    const float* x       = (const float*)d_in[1];
    const float* V       = (const float*)d_in[2];
    const float* u       = (const float*)d_in[3];
    const float* m       = (const float*)d_in[4];
    const float* W_env   = (const float*)d_in[5];
    const float* W1      = (const float*)d_in[6];
    const float* W2      = (const float*)d_in[7];
    const float* W3      = (const float*)d_in[8];
    const float* W_out   = (const float*)d_in[9];
    const int*   senders = (const int*)d_in[10];

    const int E = in_sizes[4];          // 256000
    const int NN = 16000;               // N_NODES

    // workspace layout: node_cnt[NN] | node_s[NN*64] | node_v[NN*192]
    float* node_cnt = (float*)d_ws;
    float* node_s   = node_cnt + NN;
    float* node_v   = node_s + (size_t)NN * 64;
    const size_t node_bytes = (size_t)NN * (1 + 64 + 192) * sizeof(float);

    hipMemsetAsync(d_ws, 0, node_bytes, stream);

    k_scatter<<<512, 1024, 0, stream>>>(vectors, x, m, W_env, senders,
                                        node_cnt, node_s, node_v, E);

    float* out_x = (float*)d_out;
    float* out_v = out_x + (size_t)E * 128;
    k_fused<<<512, 1024, 0, stream>>>(x, V, u, m, W1, W2, W3, W_out, senders,
                                      node_cnt, node_s, node_v,
                                      out_x, out_v, INV_SILU_C, E);
}

// Round 2
// 925.627 us; speedup vs baseline: 3.8098x; 3.8098x over previous
//
#include <hip/hip_runtime.h>
#include <math.h>

typedef short bf16x8 __attribute__((ext_vector_type(8)));
typedef float f32x4 __attribute__((ext_vector_type(4)));

#define S128 0.08838834764831845f   /* 1/sqrt(128) */
#define S256I 0.0625f               /* 1/sqrt(256) */

// ws layout (bytes)
#define WS_NODE_BYTES 16448000      /* 16000 * (1+64+192) * 4 */
#define WS_W1 16448000
#define WS_W2 (WS_W1 + 65536)
#define WS_W3 (WS_W2 + 32768)
#define WS_WO (WS_W3 + 32768)

// ---- host-side constant: SILU_C exactly as the reference computes it ----
static float compute_inv_silu_c() {
    double sum = 0.0, prev = 0.0;
    const double dz = 24.0 / 100000.0;
    for (int i = 0; i <= 100000; ++i) {
        double z = -12.0 + dz * (double)i;
        double pdf = exp(-0.5 * z * z) * 0.3989422804014327;
        double s = z / (1.0 + exp(-z));
        double f = s * s * pdf;
        if (i) sum += 0.5 * (prev + f) * dz;
        prev = f;
    }
    return (float)(1.0 / sqrt(sum));
}
static const float INV_SILU_C = compute_inv_silu_c();

// ---- device helpers ----
__device__ __forceinline__ unsigned int packbf(float a, float b) {
    union { float f; unsigned int u; } ca, cb;
    ca.f = a; cb.f = b;
    unsigned int ua = ca.u + (0x7fffu + ((ca.u >> 16) & 1u));
    unsigned int ub = cb.u + (0x7fffu + ((cb.u >> 16) & 1u));
    return (ua >> 16) | (ub & 0xffff0000u);
}
__device__ __forceinline__ unsigned short bf16r(float v) {
    union { float f; unsigned int u; } c; c.f = v;
    return (unsigned short)((c.u + (0x7fffu + ((c.u >> 16) & 1u))) >> 16);
}
__device__ __forceinline__ int swz(int row, int b) { return b ^ ((row & 7) << 4); }
__device__ __forceinline__ float nsilu(float v, float ic) {
    return v / (1.0f + __expf(-v)) * ic;
}

// =====================================================================
// k_wprep: transpose, bf16-quantize, scale-fold, and PRE-SWIZZLE weights
// into ws. Row-major [rows][k] bf16 with byte ^= (row&7)<<4 within row.
// =====================================================================
__global__ __launch_bounds__(256) void k_wprep(
    const float* __restrict__ W1, const float* __restrict__ W2,
    const float* __restrict__ W3, const float* __restrict__ Wout,
    char* __restrict__ wsb)
{
    const int t = blockIdx.x * 256 + threadIdx.x;   // 32768 threads
    if (t < 32768) {  // W1T[128][256]
        int n = t & 127, k = t >> 7;
        *(unsigned short*)(wsb + WS_W1 + n * 512 + ((k * 2) ^ ((n & 7) << 4))) =
            bf16r(W1[k * 128 + n] * S256I);
    }
    if (t < 16384) {  // W2T[128][128], W3T[128][128]
        int n = t & 127, k = t >> 7;
        *(unsigned short*)(wsb + WS_W2 + n * 256 + ((k * 2) ^ ((n & 7) << 4))) =
            bf16r(W2[k * 128 + n] * S128);
        *(unsigned short*)(wsb + WS_W3 + n * 256 + ((k * 2) ^ ((n & 7) << 4))) =
            bf16r(W3[k * 128 + n] * S128);
    }
    if (t < 8192) {   // WoutT[64][128]
        int o = t & 63, uu = t >> 6;
        *(unsigned short*)(wsb + WS_WO + o * 256 + ((uu * 2) ^ ((o & 7) << 4))) =
            bf16r(Wout[uu * 64 + o] * S128);
    }
}

// =====================================================================
// Kernel 1 (unchanged): per-edge w = (x*m)@W_env/sqrt(128); f32 atomic
// scatter into node accumulators.
// =====================================================================
__global__ __launch_bounds__(1024) void k_scatter(
    const float* __restrict__ vectors, const float* __restrict__ x,
    const float* __restrict__ m, const float* __restrict__ W_env,
    const int* __restrict__ senders,
    float* __restrict__ node_cnt, float* __restrict__ node_s,
    float* __restrict__ node_v, int E)
{
    __shared__ float sW[128 * 128];
    for (int t = threadIdx.x; t < 128 * 128; t += 1024)
        sW[t] = W_env[t] * S128;
    __syncthreads();

    const int lane = threadIdx.x & 63;
    const int gw   = (int)((blockIdx.x * 1024u + threadIdx.x) >> 6);
    const int nw   = (int)((gridDim.x * 1024u) >> 6);

    for (int e = gw; e < E; e += nw) {
        const float mv = m[e];
        const float x0 = x[(size_t)e * 128 + lane] * mv;
        const float x1 = x[(size_t)e * 128 + 64 + lane] * mv;

        float acc0 = 0.f, acc1 = 0.f;
        #pragma unroll 8
        for (int q = 0; q < 64; ++q) {
            const float xa = __shfl(x0, q);
            const float xb = __shfl(x1, q);
            acc0 += xa * sW[q * 128 + lane]      + xb * sW[(64 + q) * 128 + lane];
            acc1 += xa * sW[q * 128 + 64 + lane] + xb * sW[(64 + q) * 128 + 64 + lane];
        }

        const float vx = vectors[(size_t)e * 3 + 0];
        const float vy = vectors[(size_t)e * 3 + 1];
        const float vz = vectors[(size_t)e * 3 + 2];
        const float rn = 1.7320508075688772f / sqrtf(vx * vx + vy * vy + vz * vz);

        const int sn = senders[e];
        atomicAdd(&node_s[(size_t)sn * 64 + lane], acc0 * mv);
        const float c1 = acc1 * mv;
        float* nv = &node_v[((size_t)sn * 64 + lane) * 3];
        atomicAdd(nv + 0, c1 * vx * rn);
        atomicAdd(nv + 1, c1 * vy * rn);
        atomicAdd(nv + 2, c1 * vz * rn);
        if (lane == 0) atomicAdd(&node_cnt[sn], mv);
    }
}

// =====================================================================
// Kernel 2: gather + s_a/s_b (stash bf16 into out_x region) + build
// V_in tile in LDS + MFMA V_out = V_in @ WoutT.
// Block: 512 threads, 64 edges. M=192 rows (m = 3*e_loc + k), N=64, K=128.
// =====================================================================
__global__ __launch_bounds__(512) void k_prep_vout(
    const float* __restrict__ V, const int* __restrict__ senders,
    const float* __restrict__ node_cnt, const float* __restrict__ node_s,
    const float* __restrict__ node_v, const char* __restrict__ wsb,
    float* __restrict__ out_x, float* __restrict__ out_v, int E)
{
    __shared__ char lds[49152 + 16384];   // vin[192][128]bf16 swz | WoutT 16KB
    const int tid = threadIdx.x, l = tid & 63, wid = tid >> 6;

    {   // stage WoutT (pre-swizzled in ws -> linear copy)
        const int4* src = (const int4*)(wsb + WS_WO);
        int4 a = src[tid * 2], b = src[tid * 2 + 1];
        ((int4*)(lds + 49152))[tid * 2]     = a;
        ((int4*)(lds + 49152))[tid * 2 + 1] = b;
    }

    const int eb = blockIdx.x * 64;
    #pragma unroll 2
    for (int i = 0; i < 8; ++i) {
        const int el = wid * 8 + i;
        const int e  = eb + el;
        float Vs = 0.f, Vv0 = 0.f, Vv1 = 0.f, Vv2 = 0.f;
        float wYs = 0.f, wv0 = 0.f, wv1 = 0.f, wv2 = 0.f;
        if (e < E) {
            Vs = V[(size_t)e * 256 + l];
            const float* vp = &V[(size_t)e * 256 + 64 + l * 3];
            Vv0 = vp[0]; Vv1 = vp[1]; Vv2 = vp[2];
            const int sn = senders[e];
            const float rden = 1.0f / (node_cnt[sn] + 1e-5f);
            wYs = node_s[(size_t)sn * 64 + l] * rden;
            const float* nvp = &node_v[((size_t)sn * 64 + l) * 3];
            wv0 = nvp[0] * rden; wv1 = nvp[1] * rden; wv2 = nvp[2] * rden;
            unsigned short* sab = (unsigned short*)((char*)out_x + (size_t)e * 512);
            sab[l]      = bf16r(wYs * Vs);
            sab[64 + l] = bf16r((wv0 * Vv0 + wv1 * Vv1 + wv2 * Vv2) * 0.57735026918962576f);
        }
        // vin rows 3*el+k: cols [0,64)=v_a (u=l), [64,128)=v_b (u=64+l)
        const float vvk[3] = {Vv0, Vv1, Vv2};
        const float wvk[3] = {wv0, wv1, wv2};
        #pragma unroll
        for (int k = 0; k < 3; ++k) {
            const int row = el * 3 + k;
            *(unsigned short*)(lds + row * 256 + swz(row, l * 2))       = bf16r(wYs * vvk[k]);
            *(unsigned short*)(lds + row * 256 + swz(row, 128 + l * 2)) = bf16r(wvk[k] * Vs);
        }
    }
    __syncthreads();

    // GEMM: waves 4x2; wave = 3 m-tiles x 2 n-tiles
    const int wm = wid & 3, wn = wid >> 2;
    const int m0 = wm * 48, n0 = wn * 32;
    const int lr = l & 15, lg = l >> 4;
    f32x4 acc[3][2];
    #pragma unroll
    for (int a = 0; a < 3; ++a)
        #pragma unroll
        for (int b = 0; b < 2; ++b) acc[a][b] = (f32x4){0.f, 0.f, 0.f, 0.f};

    #pragma unroll
    for (int kk = 0; kk < 4; ++kk) {
        const int kb = kk * 64 + lg * 16;
        bf16x8 a0 = *(const bf16x8*)(lds + (m0 + lr) * 256      + swz(m0 + lr, kb));
        bf16x8 a1 = *(const bf16x8*)(lds + (m0 + 16 + lr) * 256 + swz(m0 + 16 + lr, kb));
        bf16x8 a2 = *(const bf16x8*)(lds + (m0 + 32 + lr) * 256 + swz(m0 + 32 + lr, kb));
        bf16x8 b0 = *(const bf16x8*)(lds + 49152 + (n0 + lr) * 256      + swz(n0 + lr, kb));
        bf16x8 b1 = *(const bf16x8*)(lds + 49152 + (n0 + 16 + lr) * 256 + swz(n0 + 16 + lr, kb));
        acc[0][0] = __builtin_amdgcn_mfma_f32_16x16x32_bf16(a0, b0, acc[0][0], 0, 0, 0);
        acc[0][1] = __builtin_amdgcn_mfma_f32_16x16x32_bf16(a0, b1, acc[0][1], 0, 0, 0);
        acc[1][0] = __builtin_amdgcn_mfma_f32_16x16x32_bf16(a1, b0, acc[1][0], 0, 0, 0);
        acc[1][1] = __builtin_amdgcn_mfma_f32_16x16x32_bf16(a1, b1, acc[1][1], 0, 0, 0);
        acc[2][0] = __builtin_amdgcn_mfma_f32_16x16x32_bf16(a2, b0, acc[2][0], 0, 0, 0);
        acc[2][1] = __builtin_amdgcn_mfma_f32_16x16x32_bf16(a2, b1, acc[2][1], 0, 0, 0);
    }

    #pragma unroll
    for (int mt = 0; mt < 3; ++mt)
        #pragma unroll
        for (int nt = 0; nt < 2; ++nt)
            #pragma unroll
            for (int r = 0; r < 4; ++r) {
                const int mm = m0 + mt * 16 + lg * 4 + r;
                const int el2 = mm / 3, kd = mm - el2 * 3;
                const int e = eb + el2;
                const int o = n0 + nt * 16 + lr;
                if (e < E) out_v[(size_t)e * 192 + o * 3 + kd] = acc[mt][nt][r];
            }
}

// =====================================================================
// Kernel 3: fused MLP via MFMA. Block: 512 threads, 128 edges.
// xcat[128][256]bf16 (x*m | s_a | s_b) -> W1 -> nsilu -> W2 -> nsilu -> W3 -> *u
// =====================================================================
__global__ __launch_bounds__(512) void k_mlp(
    const float* __restrict__ x, const float* __restrict__ m,
    const float* __restrict__ ug, const char* __restrict__ wsb,
    float* __restrict__ out_x, float inv_c, int E)
{
    __shared__ char lds0[65536];  // xcat; later: h [0:32K) | W2T [32K:64K)
    __shared__ char lds1[65536];  // W1T;  later: W3T [0:32K) | g [32K:64K)
    const int tid = threadIdx.x;

    {   // stage W1T (pre-swizzled) -> lds1, 128B/thread
        const int4* src = (const int4*)(wsb + WS_W1);
        int4* dst = (int4*)lds1;
        #pragma unroll
        for (int j = 0; j < 8; ++j) dst[tid * 8 + j] = src[tid * 8 + j];
    }

    const int eb = blockIdx.x * 128;
    {   // xcat prep: 4 threads per edge
        const int el = tid >> 2, q = tid & 3;
        const int e  = eb + el;
        if (e < E) {
            const float mv = m[e];
            const float4* xp = (const float4*)&x[(size_t)e * 128 + q * 32];
            #pragma unroll
            for (int j = 0; j < 4; ++j) {
                float4 A = xp[2 * j], B = xp[2 * j + 1];
                int4 w;
                w.x = packbf(A.x * mv, A.y * mv); w.y = packbf(A.z * mv, A.w * mv);
                w.z = packbf(B.x * mv, B.y * mv); w.w = packbf(B.z * mv, B.w * mv);
                *(int4*)(lds0 + el * 512 + swz(el, q * 64 + j * 16)) = w;
            }
            const int4* sp = (const int4*)((const char*)out_x + (size_t)e * 512 + q * 64);
            #pragma unroll
            for (int j = 0; j < 4; ++j) {
                int4 v = sp[j];
                *(int4*)(lds0 + el * 512 + swz(el, 256 + q * 64 + j * 16)) = v;
            }
        } else {
            const int4 z = {0, 0, 0, 0};
            #pragma unroll
            for (int j = 0; j < 4; ++j) {
                *(int4*)(lds0 + el * 512 + swz(el, q * 64 + j * 16)) = z;
                *(int4*)(lds0 + el * 512 + swz(el, 256 + q * 64 + j * 16)) = z;
            }
        }
    }
    __syncthreads();

    const int l = tid & 63, wid = tid >> 6;
    const int wm = wid >> 1, wn = wid & 1;
    const int m0 = wm * 32, n0 = wn * 64;
    const int lr = l & 15, lg = l >> 4;

    // ---- stage 1: xcat[128x256] @ W1T  (K=256) ----
    f32x4 acc[2][4];
    #pragma unroll
    for (int a = 0; a < 2; ++a)
        #pragma unroll
        for (int b = 0; b < 4; ++b) acc[a][b] = (f32x4){0.f, 0.f, 0.f, 0.f};
    #pragma unroll 2
    for (int kk = 0; kk < 8; ++kk) {
        const int kb = kk * 64 + lg * 16;
        bf16x8 a0 = *(const bf16x8*)(lds0 + (m0 + lr) * 512      + swz(m0 + lr, kb));
        bf16x8 a1 = *(const bf16x8*)(lds0 + (m0 + 16 + lr) * 512 + swz(m0 + 16 + lr, kb));
        #pragma unroll
        for (int nt = 0; nt < 4; ++nt) {
            const int row = n0 + nt * 16 + lr;
            bf16x8 bb = *(const bf16x8*)(lds1 + row * 512 + swz(row, kb));
            acc[0][nt] = __builtin_amdgcn_mfma_f32_16x16x32_bf16(a0, bb, acc[0][nt], 0, 0, 0);
            acc[1][nt] = __builtin_amdgcn_mfma_f32_16x16x32_bf16(a1, bb, acc[1][nt], 0, 0, 0);
        }
    }

    // issue W2T/W3T global loads (land during barrier)
    int4 r2[4], r3[4];
    {
        const int4* s2 = (const int4*)(wsb + WS_W2);
        const int4* s3 = (const int4*)(wsb + WS_W3);
        #pragma unroll
        for (int j = 0; j < 4; ++j) { r2[j] = s2[tid * 4 + j]; r3[j] = s3[tid * 4 + j]; }
    }
    __syncthreads();

    // write h (bf16, swizzled, stride 256B) into lds0[0:32K)
    #pragma unroll
    for (int mt = 0; mt < 2; ++mt)
        #pragma unroll
        for (int nt = 0; nt < 4; ++nt)
            #pragma unroll
            for (int r = 0; r < 4; ++r) {
                const int row = m0 + mt * 16 + lg * 4 + r;
                const int col = n0 + nt * 16 + lr;
                *(unsigned short*)(lds0 + row * 256 + swz(row, col * 2)) =
                    bf16r(nsilu(acc[mt][nt][r], inv_c));
            }
    {   // write W2T -> lds0+32K, W3T -> lds1[0:32K)
        int4* d2 = (int4*)(lds0 + 32768);
        int4* d3 = (int4*)lds1;
        #pragma unroll
        for (int j = 0; j < 4; ++j) { d2[tid * 4 + j] = r2[j]; d3[tid * 4 + j] = r3[j]; }
    }
    __syncthreads();

    // ---- stage 2: h @ W2T (K=128) ----
    f32x4 acc2[2][4];
    #pragma unroll
    for (int a = 0; a < 2; ++a)
        #pragma unroll
        for (int b = 0; b < 4; ++b) acc2[a][b] = (f32x4){0.f, 0.f, 0.f, 0.f};
    #pragma unroll
    for (int kk = 0; kk < 4; ++kk) {
        const int kb = kk * 64 + lg * 16;
        bf16x8 a0 = *(const bf16x8*)(lds0 + (m0 + lr) * 256      + swz(m0 + lr, kb));
        bf16x8 a1 = *(const bf16x8*)(lds0 + (m0 + 16 + lr) * 256 + swz(m0 + 16 + lr, kb));
        #pragma unroll
        for (int nt = 0; nt < 4; ++nt) {
            const int row = n0 + nt * 16 + lr;
            bf16x8 bb = *(const bf16x8*)(lds0 + 32768 + row * 256 + swz(row, kb));
            acc2[0][nt] = __builtin_amdgcn_mfma_f32_16x16x32_bf16(a0, bb, acc2[0][nt], 0, 0, 0);
            acc2[1][nt] = __builtin_amdgcn_mfma_f32_16x16x32_bf16(a1, bb, acc2[1][nt], 0, 0, 0);
        }
    }
    // write g -> lds1+32K (no barrier needed before: disjoint from stage-2 reads)
    #pragma unroll
    for (int mt = 0; mt < 2; ++mt)
        #pragma unroll
        for (int nt = 0; nt < 4; ++nt)
            #pragma unroll
            for (int r = 0; r < 4; ++r) {
                const int row = m0 + mt * 16 + lg * 4 + r;
                const int col = n0 + nt * 16 + lr;
                *(unsigned short*)(lds1 + 32768 + row * 256 + swz(row, col * 2)) =
                    bf16r(nsilu(acc2[mt][nt][r], inv_c));
            }
    __syncthreads();

    // ---- stage 3: g @ W3T (K=128), scale by u, store ----
    f32x4 acc3[2][4];
    #pragma unroll
    for (int a = 0; a < 2; ++a)
        #pragma unroll
        for (int b = 0; b < 4; ++b) acc3[a][b] = (f32x4){0.f, 0.f, 0.f, 0.f};
    #pragma unroll
    for (int kk = 0; kk < 4; ++kk) {
        const int kb = kk * 64 + lg * 16;
        bf16x8 a0 = *(const bf16x8*)(lds1 + 32768 + (m0 + lr) * 256      + swz(m0 + lr, kb));
        bf16x8 a1 = *(const bf16x8*)(lds1 + 32768 + (m0 + 16 + lr) * 256 + swz(m0 + 16 + lr, kb));
        #pragma unroll
        for (int nt = 0; nt < 4; ++nt) {
            const int row = n0 + nt * 16 + lr;
            bf16x8 bb = *(const bf16x8*)(lds1 + row * 256 + swz(row, kb));
            acc3[0][nt] = __builtin_amdgcn_mfma_f32_16x16x32_bf16(a0, bb, acc3[0][nt], 0, 0, 0);
            acc3[1][nt] = __builtin_amdgcn_mfma_f32_16x16x32_bf16(a1, bb, acc3[1][nt], 0, 0, 0);
        }
    }
    #pragma unroll
    for (int mt = 0; mt < 2; ++mt)
        #pragma unroll
        for (int r = 0; r < 4; ++r) {
            const int e = eb + m0 + mt * 16 + lg * 4 + r;
            if (e < E) {
                const float uu = ug[e];
                #pragma unroll
                for (int nt = 0; nt < 4; ++nt)
                    out_x[(size_t)e * 128 + n0 + nt * 16 + lr] = uu * acc3[mt][nt][r];
            }
        }
}

// =====================================================================
extern "C" void kernel_launch(void* const* d_in, const int* in_sizes, int n_in,
                              void* d_out, int out_size, void* d_ws, size_t ws_size,
                              hipStream_t stream) {
    const float* vectors = (const float*)d_in[0];
    const float* x       = (const float*)d_in[1];
    const float* V       = (const float*)d_in[2];
    const float* u       = (const float*)d_in[3];
    const float* m       = (const float*)d_in[4];
    const float* W_env   = (const float*)d_in[5];
    const float* W1      = (const float*)d_in[6];
    const float* W2      = (const float*)d_in[7];
    const float* W3      = (const float*)d_in[8];
    const float* W_out   = (const float*)d_in[9];
    const int*   senders = (const int*)d_in[10];

    const int E  = in_sizes[4];   // 256000
    const int NN = 16000;

    char*  wsb      = (char*)d_ws;
    float* node_cnt = (float*)d_ws;
    float* node_s   = node_cnt + NN;
    float* node_v   = node_s + (size_t)NN * 64;

    hipMemsetAsync(d_ws, 0, WS_NODE_BYTES, stream);

    k_wprep<<<128, 256, 0, stream>>>(W1, W2, W3, W_out, wsb);

    k_scatter<<<512, 1024, 0, stream>>>(vectors, x, m, W_env, senders,
                                        node_cnt, node_s, node_v, E);

    float* out_x = (float*)d_out;
    float* out_v = out_x + (size_t)E * 128;

    k_prep_vout<<<(E + 63) / 64, 512, 0, stream>>>(V, senders, node_cnt, node_s,
                                                   node_v, wsb, out_x, out_v, E);

    k_mlp<<<(E + 127) / 128, 512, 0, stream>>>(x, m, u, wsb, out_x, INV_SILU_C, E);
}

// Round 3
// 496.618 us; speedup vs baseline: 7.1010x; 1.8639x over previous
//
#include <hip/hip_runtime.h>
#include <math.h>

typedef short bf16x8 __attribute__((ext_vector_type(8)));
typedef float f32x4 __attribute__((ext_vector_type(4)));

#define S128 0.08838834764831845f   /* 1/sqrt(128) */
#define S256I 0.0625f               /* 1/sqrt(256) */
#define NN_NODES 16000

// ws layout (bytes)
#define WS_COUNTS   16448000            /* int[16000] (node arrays occupy [0,16448000)) */
#define WS_OFFSETS  (WS_COUNTS + 64000)
#define WS_CURSOR   (WS_OFFSETS + 64000)
#define WS_ORDER    (WS_CURSOR + 64000) /* int[256000] */
#define WS_W1 (WS_ORDER + 1024000)
#define WS_W2 (WS_W1 + 65536)
#define WS_W3 (WS_W2 + 32768)
#define WS_WO (WS_W3 + 32768)
#define WS_WE (WS_WO + 16384)           /* +32768 -> total ~17.9 MB */

// ---- host-side constant: SILU_C exactly as the reference computes it ----
static float compute_inv_silu_c() {
    double sum = 0.0, prev = 0.0;
    const double dz = 24.0 / 100000.0;
    for (int i = 0; i <= 100000; ++i) {
        double z = -12.0 + dz * (double)i;
        double pdf = exp(-0.5 * z * z) * 0.3989422804014327;
        double s = z / (1.0 + exp(-z));
        double f = s * s * pdf;
        if (i) sum += 0.5 * (prev + f) * dz;
        prev = f;
    }
    return (float)(1.0 / sqrt(sum));
}
static const float INV_SILU_C = compute_inv_silu_c();

// ---- device helpers ----
__device__ __forceinline__ unsigned int packbf(float a, float b) {
    union { float f; unsigned int u; } ca, cb;
    ca.f = a; cb.f = b;
    unsigned int ua = ca.u + (0x7fffu + ((ca.u >> 16) & 1u));
    unsigned int ub = cb.u + (0x7fffu + ((cb.u >> 16) & 1u));
    return (ua >> 16) | (ub & 0xffff0000u);
}
__device__ __forceinline__ unsigned short bf16r(float v) {
    union { float f; unsigned int u; } c; c.f = v;
    return (unsigned short)((c.u + (0x7fffu + ((c.u >> 16) & 1u))) >> 16);
}
__device__ __forceinline__ float bflo(unsigned int u) { return __uint_as_float(u << 16); }
__device__ __forceinline__ float bfhi(unsigned int u) { return __uint_as_float(u & 0xffff0000u); }
__device__ __forceinline__ int swz(int row, int b) { return b ^ ((row & 7) << 4); }
__device__ __forceinline__ float nsilu(float v, float ic) {
    return v / (1.0f + __expf(-v)) * ic;
}

// =====================================================================
// k_wprep: transpose, bf16-quantize, scale-fold, PRE-SWIZZLE weights.
// WenvT rows are interleave-permuted: row j -> orig col (j&1? 64+j/2 : j/2)
// so GEMM output row layout is (w0[0],w1[0],w0[1],w1[1],...).
// =====================================================================
__global__ __launch_bounds__(256) void k_wprep(
    const float* __restrict__ W1, const float* __restrict__ W2,
    const float* __restrict__ W3, const float* __restrict__ Wout,
    const float* __restrict__ Wenv, char* __restrict__ wsb)
{
    const int t = blockIdx.x * 256 + threadIdx.x;   // 32768 threads
    if (t < 32768) {  // W1T[128][256]
        int n = t & 127, k = t >> 7;
        *(unsigned short*)(wsb + WS_W1 + n * 512 + ((k * 2) ^ ((n & 7) << 4))) =
            bf16r(W1[k * 128 + n] * S256I);
    }
    if (t < 16384) {  // W2T, W3T [128][128]
        int n = t & 127, k = t >> 7;
        *(unsigned short*)(wsb + WS_W2 + n * 256 + ((k * 2) ^ ((n & 7) << 4))) =
            bf16r(W2[k * 128 + n] * S128);
        *(unsigned short*)(wsb + WS_W3 + n * 256 + ((k * 2) ^ ((n & 7) << 4))) =
            bf16r(W3[k * 128 + n] * S128);
    }
    if (t < 16384) {  // WenvT[128][128], interleaved row permutation
        int j = t & 127, k = t >> 7;
        int c = (j & 1) ? 64 + (j >> 1) : (j >> 1);
        *(unsigned short*)(wsb + WS_WE + j * 256 + ((k * 2) ^ ((j & 7) << 4))) =
            bf16r(Wenv[k * 128 + c] * S128);
    }
    if (t < 8192) {   // WoutT[64][128]
        int o = t & 63, uu = t >> 6;
        *(unsigned short*)(wsb + WS_WO + o * 256 + ((uu * 2) ^ ((o & 7) << 4))) =
            bf16r(Wout[uu * 64 + o] * S128);
    }
}

// =====================================================================
// sort-by-sender chain
// =====================================================================
__global__ __launch_bounds__(1024) void k_hist(
    const int* __restrict__ senders, int* __restrict__ counts, int E)
{
    const int e = blockIdx.x * 1024 + threadIdx.x;
    if (e < E) atomicAdd(&counts[senders[e]], 1);
}

__global__ __launch_bounds__(1024) void k_scan(
    const int* __restrict__ counts, int* __restrict__ offsets,
    int* __restrict__ cursor)
{
    __shared__ int part[1024];
    const int t = threadIdx.x;
    const int s0 = t * 16;
    const int s1 = (s0 + 16 < NN_NODES) ? s0 + 16 : NN_NODES;
    int s = 0;
    for (int i = s0; i < s1; ++i) s += counts[i];
    part[t] = s;
    __syncthreads();
    for (int off = 1; off < 1024; off <<= 1) {
        int v = part[t];
        if (t >= off) v += part[t - off];
        __syncthreads();
        part[t] = v;
        __syncthreads();
    }
    int run = t ? part[t - 1] : 0;
    for (int i = s0; i < s1; ++i) {
        offsets[i] = run; cursor[i] = run; run += counts[i];
    }
}

__global__ __launch_bounds__(1024) void k_binfill(
    const int* __restrict__ senders, int* __restrict__ cursor,
    int* __restrict__ order, int E)
{
    const int e = blockIdx.x * 1024 + threadIdx.x;
    if (e < E) {
        const int p = atomicAdd(&cursor[senders[e]], 1);
        order[p] = e;
    }
}

// =====================================================================
// k_env: w = (x*m) @ WenvT via MFMA. 128 edges/block. Output bf16
// interleaved rows (w0[l],w1[l]) pairs, written to scratch (out_v region).
// =====================================================================
__global__ __launch_bounds__(512) void k_env(
    const float* __restrict__ x, const float* __restrict__ m,
    const char* __restrict__ wsb, char* __restrict__ wout, int E)
{
    __shared__ char lds[65536];  // [0,32K): xm swz / results; [32K,64K): WenvT
    const int tid = threadIdx.x;

    {   // stage WenvT (pre-swizzled): 64B/thread
        const int4* src = (const int4*)(wsb + WS_WE);
        int4* dst = (int4*)(lds + 32768);
        #pragma unroll
        for (int j = 0; j < 4; ++j) dst[tid * 4 + j] = src[tid * 4 + j];
    }

    const int eb = blockIdx.x * 128;
    {   // xm tile: 4 threads/edge, 32 floats each -> 4 int4 bf16 writes
        const int el = tid >> 2, q = tid & 3;
        const int e = eb + el;
        if (e < E) {
            const float mv = m[e];
            const float4* xp = (const float4*)&x[(size_t)e * 128 + q * 32];
            #pragma unroll
            for (int j = 0; j < 4; ++j) {
                float4 A = xp[2 * j], B = xp[2 * j + 1];
                int4 w;
                w.x = packbf(A.x * mv, A.y * mv); w.y = packbf(A.z * mv, A.w * mv);
                w.z = packbf(B.x * mv, B.y * mv); w.w = packbf(B.z * mv, B.w * mv);
                *(int4*)(lds + el * 256 + swz(el, q * 64 + j * 16)) = w;
            }
        } else {
            const int4 z = {0, 0, 0, 0};
            #pragma unroll
            for (int j = 0; j < 4; ++j)
                *(int4*)(lds + el * 256 + swz(el, q * 64 + j * 16)) = z;
        }
    }
    __syncthreads();

    const int l = tid & 63, wid = tid >> 6;
    const int wm = wid & 3, wn = wid >> 2;
    const int m0 = wm * 32, n0 = wn * 64;
    const int lr = l & 15, lg = l >> 4;

    f32x4 acc[2][4];
    #pragma unroll
    for (int a = 0; a < 2; ++a)
        #pragma unroll
        for (int b = 0; b < 4; ++b) acc[a][b] = (f32x4){0.f, 0.f, 0.f, 0.f};

    #pragma unroll
    for (int kk = 0; kk < 4; ++kk) {
        const int kb = kk * 64 + lg * 16;
        bf16x8 a0 = *(const bf16x8*)(lds + (m0 + lr) * 256      + swz(m0 + lr, kb));
        bf16x8 a1 = *(const bf16x8*)(lds + (m0 + 16 + lr) * 256 + swz(m0 + 16 + lr, kb));
        #pragma unroll
        for (int nt = 0; nt < 4; ++nt) {
            const int row = n0 + nt * 16 + lr;
            bf16x8 bb = *(const bf16x8*)(lds + 32768 + row * 256 + swz(row, kb));
            acc[0][nt] = __builtin_amdgcn_mfma_f32_16x16x32_bf16(a0, bb, acc[0][nt], 0, 0, 0);
            acc[1][nt] = __builtin_amdgcn_mfma_f32_16x16x32_bf16(a1, bb, acc[1][nt], 0, 0, 0);
        }
    }
    __syncthreads();

    // results -> lds[0:32K) linear [128 rows][256B], then coalesced copy-out
    #pragma unroll
    for (int mt = 0; mt < 2; ++mt)
        #pragma unroll
        for (int nt = 0; nt < 4; ++nt)
            #pragma unroll
            for (int r = 0; r < 4; ++r) {
                const int row = m0 + mt * 16 + lg * 4 + r;
                const int col = n0 + nt * 16 + lr;
                *(unsigned short*)(lds + row * 256 + col * 2) = bf16r(acc[mt][nt][r]);
            }
    __syncthreads();
    {
        const int4* s = (const int4*)lds;
        int4* d = (int4*)(wout + (size_t)eb * 256);
        #pragma unroll
        for (int j = 0; j < 4; ++j) d[tid * 4 + j] = s[tid * 4 + j];
    }
}

// =====================================================================
// k_gather: one wave per node; accumulate sorted edges' w rows; write
// node accumulators once (no atomics, no pre-zeroing needed).
// =====================================================================
__global__ __launch_bounds__(256) void k_gather(
    const char* __restrict__ wvb, const float* __restrict__ vectors,
    const float* __restrict__ m, const int* __restrict__ counts,
    const int* __restrict__ offsets, const int* __restrict__ order,
    float* __restrict__ node_cnt, float* __restrict__ node_s,
    float* __restrict__ node_v)
{
    const int l = threadIdx.x & 63, wid = threadIdx.x >> 6;
    const int n = blockIdx.x * 4 + wid;
    if (n >= NN_NODES) return;
    const int cnt = counts[n], base = offsets[n];

    float as = 0.f, a0 = 0.f, a1 = 0.f, a2 = 0.f, am = 0.f;
    for (int i = 0; i < cnt; ++i) {
        const int e = order[base + i];
        const unsigned int wv = *(const unsigned int*)(wvb + (size_t)e * 256 + l * 4);
        const float mm = m[e];
        const float vx = vectors[(size_t)e * 3 + 0];
        const float vy = vectors[(size_t)e * 3 + 1];
        const float vz = vectors[(size_t)e * 3 + 2];
        const float rn = 1.7320508075688772f / sqrtf(vx * vx + vy * vy + vz * vz);
        const float w0 = bflo(wv) * mm;
        const float c1 = bfhi(wv) * mm * rn;
        as += w0; am += mm;
        a0 += c1 * vx; a1 += c1 * vy; a2 += c1 * vz;
    }
    if (l == 0) node_cnt[n] = am;
    node_s[(size_t)n * 64 + l] = as;
    float* nv = &node_v[((size_t)n * 64 + l) * 3];
    nv[0] = a0; nv[1] = a1; nv[2] = a2;
}

// =====================================================================
// k_prep_vout (unchanged from R2)
// =====================================================================
__global__ __launch_bounds__(512) void k_prep_vout(
    const float* __restrict__ V, const int* __restrict__ senders,
    const float* __restrict__ node_cnt, const float* __restrict__ node_s,
    const float* __restrict__ node_v, const char* __restrict__ wsb,
    float* __restrict__ out_x, float* __restrict__ out_v, int E)
{
    __shared__ char lds[49152 + 16384];
    const int tid = threadIdx.x, l = tid & 63, wid = tid >> 6;

    {
        const int4* src = (const int4*)(wsb + WS_WO);
        int4 a = src[tid * 2], b = src[tid * 2 + 1];
        ((int4*)(lds + 49152))[tid * 2]     = a;
        ((int4*)(lds + 49152))[tid * 2 + 1] = b;
    }

    const int eb = blockIdx.x * 64;
    #pragma unroll 2
    for (int i = 0; i < 8; ++i) {
        const int el = wid * 8 + i;
        const int e  = eb + el;
        float Vs = 0.f, Vv0 = 0.f, Vv1 = 0.f, Vv2 = 0.f;
        float wYs = 0.f, wv0 = 0.f, wv1 = 0.f, wv2 = 0.f;
        if (e < E) {
            Vs = V[(size_t)e * 256 + l];
            const float* vp = &V[(size_t)e * 256 + 64 + l * 3];
            Vv0 = vp[0]; Vv1 = vp[1]; Vv2 = vp[2];
            const int sn = senders[e];
            const float rden = 1.0f / (node_cnt[sn] + 1e-5f);
            wYs = node_s[(size_t)sn * 64 + l] * rden;
            const float* nvp = &node_v[((size_t)sn * 64 + l) * 3];
            wv0 = nvp[0] * rden; wv1 = nvp[1] * rden; wv2 = nvp[2] * rden;
            unsigned short* sab = (unsigned short*)((char*)out_x + (size_t)e * 512);
            sab[l]      = bf16r(wYs * Vs);
            sab[64 + l] = bf16r((wv0 * Vv0 + wv1 * Vv1 + wv2 * Vv2) * 0.57735026918962576f);
        }
        const float vvk[3] = {Vv0, Vv1, Vv2};
        const float wvk[3] = {wv0, wv1, wv2};
        #pragma unroll
        for (int k = 0; k < 3; ++k) {
            const int row = el * 3 + k;
            *(unsigned short*)(lds + row * 256 + swz(row, l * 2))       = bf16r(wYs * vvk[k]);
            *(unsigned short*)(lds + row * 256 + swz(row, 128 + l * 2)) = bf16r(wvk[k] * Vs);
        }
    }
    __syncthreads();

    const int wm = wid & 3, wn = wid >> 2;
    const int m0 = wm * 48, n0 = wn * 32;
    const int lr = l & 15, lg = l >> 4;
    f32x4 acc[3][2];
    #pragma unroll
    for (int a = 0; a < 3; ++a)
        #pragma unroll
        for (int b = 0; b < 2; ++b) acc[a][b] = (f32x4){0.f, 0.f, 0.f, 0.f};

    #pragma unroll
    for (int kk = 0; kk < 4; ++kk) {
        const int kb = kk * 64 + lg * 16;
        bf16x8 a0 = *(const bf16x8*)(lds + (m0 + lr) * 256      + swz(m0 + lr, kb));
        bf16x8 a1 = *(const bf16x8*)(lds + (m0 + 16 + lr) * 256 + swz(m0 + 16 + lr, kb));
        bf16x8 a2 = *(const bf16x8*)(lds + (m0 + 32 + lr) * 256 + swz(m0 + 32 + lr, kb));
        bf16x8 b0 = *(const bf16x8*)(lds + 49152 + (n0 + lr) * 256      + swz(n0 + lr, kb));
        bf16x8 b1 = *(const bf16x8*)(lds + 49152 + (n0 + 16 + lr) * 256 + swz(n0 + 16 + lr, kb));
        acc[0][0] = __builtin_amdgcn_mfma_f32_16x16x32_bf16(a0, b0, acc[0][0], 0, 0, 0);
        acc[0][1] = __builtin_amdgcn_mfma_f32_16x16x32_bf16(a0, b1, acc[0][1], 0, 0, 0);
        acc[1][0] = __builtin_amdgcn_mfma_f32_16x16x32_bf16(a1, b0, acc[1][0], 0, 0, 0);
        acc[1][1] = __builtin_amdgcn_mfma_f32_16x16x32_bf16(a1, b1, acc[1][1], 0, 0, 0);
        acc[2][0] = __builtin_amdgcn_mfma_f32_16x16x32_bf16(a2, b0, acc[2][0], 0, 0, 0);
        acc[2][1] = __builtin_amdgcn_mfma_f32_16x16x32_bf16(a2, b1, acc[2][1], 0, 0, 0);
    }

    #pragma unroll
    for (int mt = 0; mt < 3; ++mt)
        #pragma unroll
        for (int nt = 0; nt < 2; ++nt)
            #pragma unroll
            for (int r = 0; r < 4; ++r) {
                const int mm = m0 + mt * 16 + lg * 4 + r;
                const int el2 = mm / 3, kd = mm - el2 * 3;
                const int e = eb + el2;
                const int o = n0 + nt * 16 + lr;
                if (e < E) out_v[(size_t)e * 192 + o * 3 + kd] = acc[mt][nt][r];
            }
}

// =====================================================================
// k_mlp (unchanged from R2)
// =====================================================================
__global__ __launch_bounds__(512) void k_mlp(
    const float* __restrict__ x, const float* __restrict__ m,
    const float* __restrict__ ug, const char* __restrict__ wsb,
    float* __restrict__ out_x, float inv_c, int E)
{
    __shared__ char lds0[65536];
    __shared__ char lds1[65536];
    const int tid = threadIdx.x;

    {
        const int4* src = (const int4*)(wsb + WS_W1);
        int4* dst = (int4*)lds1;
        #pragma unroll
        for (int j = 0; j < 8; ++j) dst[tid * 8 + j] = src[tid * 8 + j];
    }

    const int eb = blockIdx.x * 128;
    {
        const int el = tid >> 2, q = tid & 3;
        const int e  = eb + el;
        if (e < E) {
            const float mv = m[e];
            const float4* xp = (const float4*)&x[(size_t)e * 128 + q * 32];
            #pragma unroll
            for (int j = 0; j < 4; ++j) {
                float4 A = xp[2 * j], B = xp[2 * j + 1];
                int4 w;
                w.x = packbf(A.x * mv, A.y * mv); w.y = packbf(A.z * mv, A.w * mv);
                w.z = packbf(B.x * mv, B.y * mv); w.w = packbf(B.z * mv, B.w * mv);
                *(int4*)(lds0 + el * 512 + swz(el, q * 64 + j * 16)) = w;
            }
            const int4* sp = (const int4*)((const char*)out_x + (size_t)e * 512 + q * 64);
            #pragma unroll
            for (int j = 0; j < 4; ++j) {
                int4 v = sp[j];
                *(int4*)(lds0 + el * 512 + swz(el, 256 + q * 64 + j * 16)) = v;
            }
        } else {
            const int4 z = {0, 0, 0, 0};
            #pragma unroll
            for (int j = 0; j < 4; ++j) {
                *(int4*)(lds0 + el * 512 + swz(el, q * 64 + j * 16)) = z;
                *(int4*)(lds0 + el * 512 + swz(el, 256 + q * 64 + j * 16)) = z;
            }
        }
    }
    __syncthreads();

    const int l = tid & 63, wid = tid >> 6;
    const int wm = wid >> 1, wn = wid & 1;
    const int m0 = wm * 32, n0 = wn * 64;
    const int lr = l & 15, lg = l >> 4;

    f32x4 acc[2][4];
    #pragma unroll
    for (int a = 0; a < 2; ++a)
        #pragma unroll
        for (int b = 0; b < 4; ++b) acc[a][b] = (f32x4){0.f, 0.f, 0.f, 0.f};
    #pragma unroll 2
    for (int kk = 0; kk < 8; ++kk) {
        const int kb = kk * 64 + lg * 16;
        bf16x8 a0 = *(const bf16x8*)(lds0 + (m0 + lr) * 512      + swz(m0 + lr, kb));
        bf16x8 a1 = *(const bf16x8*)(lds0 + (m0 + 16 + lr) * 512 + swz(m0 + 16 + lr, kb));
        #pragma unroll
        for (int nt = 0; nt < 4; ++nt) {
            const int row = n0 + nt * 16 + lr;
            bf16x8 bb = *(const bf16x8*)(lds1 + row * 512 + swz(row, kb));
            acc[0][nt] = __builtin_amdgcn_mfma_f32_16x16x32_bf16(a0, bb, acc[0][nt], 0, 0, 0);
            acc[1][nt] = __builtin_amdgcn_mfma_f32_16x16x32_bf16(a1, bb, acc[1][nt], 0, 0, 0);
        }
    }

    int4 r2[4], r3[4];
    {
        const int4* s2 = (const int4*)(wsb + WS_W2);
        const int4* s3 = (const int4*)(wsb + WS_W3);
        #pragma unroll
        for (int j = 0; j < 4; ++j) { r2[j] = s2[tid * 4 + j]; r3[j] = s3[tid * 4 + j]; }
    }
    __syncthreads();

    #pragma unroll
    for (int mt = 0; mt < 2; ++mt)
        #pragma unroll
        for (int nt = 0; nt < 4; ++nt)
            #pragma unroll
            for (int r = 0; r < 4; ++r) {
                const int row = m0 + mt * 16 + lg * 4 + r;
                const int col = n0 + nt * 16 + lr;
                *(unsigned short*)(lds0 + row * 256 + swz(row, col * 2)) =
                    bf16r(nsilu(acc[mt][nt][r], inv_c));
            }
    {
        int4* d2 = (int4*)(lds0 + 32768);
        int4* d3 = (int4*)lds1;
        #pragma unroll
        for (int j = 0; j < 4; ++j) { d2[tid * 4 + j] = r2[j]; d3[tid * 4 + j] = r3[j]; }
    }
    __syncthreads();

    f32x4 acc2[2][4];
    #pragma unroll
    for (int a = 0; a < 2; ++a)
        #pragma unroll
        for (int b = 0; b < 4; ++b) acc2[a][b] = (f32x4){0.f, 0.f, 0.f, 0.f};
    #pragma unroll
    for (int kk = 0; kk < 4; ++kk) {
        const int kb = kk * 64 + lg * 16;
        bf16x8 a0 = *(const bf16x8*)(lds0 + (m0 + lr) * 256      + swz(m0 + lr, kb));
        bf16x8 a1 = *(const bf16x8*)(lds0 + (m0 + 16 + lr) * 256 + swz(m0 + 16 + lr, kb));
        #pragma unroll
        for (int nt = 0; nt < 4; ++nt) {
            const int row = n0 + nt * 16 + lr;
            bf16x8 bb = *(const bf16x8*)(lds0 + 32768 + row * 256 + swz(row, kb));
            acc2[0][nt] = __builtin_amdgcn_mfma_f32_16x16x32_bf16(a0, bb, acc2[0][nt], 0, 0, 0);
            acc2[1][nt] = __builtin_amdgcn_mfma_f32_16x16x32_bf16(a1, bb, acc2[1][nt], 0, 0, 0);
        }
    }
    #pragma unroll
    for (int mt = 0; mt < 2; ++mt)
        #pragma unroll
        for (int nt = 0; nt < 4; ++nt)
            #pragma unroll
            for (int r = 0; r < 4; ++r) {
                const int row = m0 + mt * 16 + lg * 4 + r;
                const int col = n0 + nt * 16 + lr;
                *(unsigned short*)(lds1 + 32768 + row * 256 + swz(row, col * 2)) =
                    bf16r(nsilu(acc2[mt][nt][r], inv_c));
            }
    __syncthreads();

    f32x4 acc3[2][4];
    #pragma unroll
    for (int a = 0; a < 2; ++a)
        #pragma unroll
        for (int b = 0; b < 4; ++b) acc3[a][b] = (f32x4){0.f, 0.f, 0.f, 0.f};
    #pragma unroll
    for (int kk = 0; kk < 4; ++kk) {
        const int kb = kk * 64 + lg * 16;
        bf16x8 a0 = *(const bf16x8*)(lds1 + 32768 + (m0 + lr) * 256      + swz(m0 + lr, kb));
        bf16x8 a1 = *(const bf16x8*)(lds1 + 32768 + (m0 + 16 + lr) * 256 + swz(m0 + 16 + lr, kb));
        #pragma unroll
        for (int nt = 0; nt < 4; ++nt) {
            const int row = n0 + nt * 16 + lr;
            bf16x8 bb = *(const bf16x8*)(lds1 + row * 256 + swz(row, kb));
            acc3[0][nt] = __builtin_amdgcn_mfma_f32_16x16x32_bf16(a0, bb, acc3[0][nt], 0, 0, 0);
            acc3[1][nt] = __builtin_amdgcn_mfma_f32_16x16x32_bf16(a1, bb, acc3[1][nt], 0, 0, 0);
        }
    }
    #pragma unroll
    for (int mt = 0; mt < 2; ++mt)
        #pragma unroll
        for (int r = 0; r < 4; ++r) {
            const int e = eb + m0 + mt * 16 + lg * 4 + r;
            if (e < E) {
                const float uu = ug[e];
                #pragma unroll
                for (int nt = 0; nt < 4; ++nt)
                    out_x[(size_t)e * 128 + n0 + nt * 16 + lr] = uu * acc3[mt][nt][r];
            }
        }
}

// =====================================================================
extern "C" void kernel_launch(void* const* d_in, const int* in_sizes, int n_in,
                              void* d_out, int out_size, void* d_ws, size_t ws_size,
                              hipStream_t stream) {
    const float* vectors = (const float*)d_in[0];
    const float* x       = (const float*)d_in[1];
    const float* V       = (const float*)d_in[2];
    const float* u       = (const float*)d_in[3];
    const float* m       = (const float*)d_in[4];
    const float* W_env   = (const float*)d_in[5];
    const float* W1      = (const float*)d_in[6];
    const float* W2      = (const float*)d_in[7];
    const float* W3      = (const float*)d_in[8];
    const float* W_out   = (const float*)d_in[9];
    const int*   senders = (const int*)d_in[10];

    const int E = in_sizes[4];   // 256000

    char*  wsb      = (char*)d_ws;
    float* node_cnt = (float*)d_ws;
    float* node_s   = node_cnt + NN_NODES;
    float* node_v   = node_s + (size_t)NN_NODES * 64;
    int* counts  = (int*)(wsb + WS_COUNTS);
    int* offsets = (int*)(wsb + WS_OFFSETS);
    int* cursor  = (int*)(wsb + WS_CURSOR);
    int* order   = (int*)(wsb + WS_ORDER);

    float* out_x = (float*)d_out;
    float* out_v = out_x + (size_t)E * 128;
    char*  wvb   = (char*)out_v;   // w scratch lives in out_v region

    hipMemsetAsync(counts, 0, 64000, stream);

    k_wprep<<<128, 256, 0, stream>>>(W1, W2, W3, W_out, W_env, wsb);
    k_hist<<<(E + 1023) / 1024, 1024, 0, stream>>>(senders, counts, E);
    k_scan<<<1, 1024, 0, stream>>>(counts, offsets, cursor);
    k_binfill<<<(E + 1023) / 1024, 1024, 0, stream>>>(senders, cursor, order, E);
    k_env<<<(E + 127) / 128, 512, 0, stream>>>(x, m, wsb, wvb, E);
    k_gather<<<(NN_NODES + 3) / 4, 256, 0, stream>>>(wvb, vectors, m, counts,
                                                     offsets, order,
                                                     node_cnt, node_s, node_v);
    k_prep_vout<<<(E + 63) / 64, 512, 0, stream>>>(V, senders, node_cnt, node_s,
                                                   node_v, wsb, out_x, out_v, E);
    k_mlp<<<(E + 127) / 128, 512, 0, stream>>>(x, m, u, wsb, out_x, INV_SILU_C, E);
}